// Round 4
// baseline (377.009 us; speedup 1.0000x reference)
//
#include <hip/hip_runtime.h>
#include <hip/hip_bf16.h>

// Problem constants (CausalSelfAttention): D_MODEL=1024, H=16, Dh=64, B=4, T=2048
#define T_SEQ   2048
#define HEADS   16
#define DH      64
#define DMODEL  1024
#define EQKV    3072   // 3*H*Dh

typedef __attribute__((ext_vector_type(8)))  __bf16 bf16x8;
typedef __attribute__((ext_vector_type(4)))  float  f32x4;
typedef __attribute__((ext_vector_type(16))) float  f32x16;
typedef unsigned short ushort_t;
typedef unsigned int   uint_t;

__device__ __forceinline__ ushort_t f2bfu(float x) {
    union { float f; uint_t u; } c; c.f = x;
    uint_t u = c.u;
    uint_t r = (u + 0x7fffu + ((u >> 16) & 1u)) >> 16;
    return (ushort_t)r;
}

// pack 2 f32 -> u32 holding 2 bf16 (lo = first arg)
__device__ __forceinline__ uint_t cvtpk(float lo, float hi) {
    uint_t r;
    asm volatile("v_cvt_pk_bf16_f32 %0, %1, %2" : "=v"(r) : "v"(lo), "v"(hi));
    return r;
}

// async global->LDS, 16B per lane; LDS dest is wave-uniform base + lane*16
__device__ __forceinline__ void gload16(const ushort_t* g, ushort_t* l) {
    __builtin_amdgcn_global_load_lds(
        (const __attribute__((address_space(1))) void*)g,
        (__attribute__((address_space(3))) void*)l,
        16, 0, 0);
}

// ---------------------------------------------------------------------------
// fp32 -> bf16 conversion (vectorized float4 in, 4 bf16 out)
// ---------------------------------------------------------------------------
__global__ void cvt_f32_bf16(const float* __restrict__ in, ushort_t* __restrict__ out, int n4) {
    int i = blockIdx.x * blockDim.x + threadIdx.x;
    if (i >= n4) return;
    const float4 v = ((const float4*)in)[i];
    ushort_t r0 = f2bfu(v.x), r1 = f2bfu(v.y), r2 = f2bfu(v.z), r3 = f2bfu(v.w);
    uint_t lo = (uint_t)r0 | ((uint_t)r1 << 16);
    uint_t hi = (uint_t)r2 | ((uint_t)r3 << 16);
    ((uint2*)out)[i] = make_uint2(lo, hi);
}

// ---------------------------------------------------------------------------
// bf16 GEMM: C[M][N] = A[M][K] * Bt[N][K]^T   (row-major bf16 raw ushort)
// 128x128 tile, BK=32, 4 waves (2x2), each wave 64x64 (4x4 16x16x32 frags).
// Staging via global_load_lds width-16 into LINEAR [128][32] LDS (m97 ladder):
// chunk c (=wid*2+it) covers rows c*16..c*16+15; lane l -> row c*16+(l>>2),
// col (l&3)*8; LDS byte offset = l*16 -> exact row-major order.
// ---------------------------------------------------------------------------
#define BM 128
#define BN 128
#define BK 32

template<bool OUT_BF16>
__global__ __launch_bounds__(256) void gemm_bt(const ushort_t* __restrict__ A,
                                               const ushort_t* __restrict__ Bt,
                                               void* __restrict__ Cv,
                                               int M, int N, int K) {
    __shared__ __align__(16) ushort_t As[BM * BK];   // linear row-major 128x32
    __shared__ __align__(16) ushort_t Bs[BN * BK];

    const int tid  = threadIdx.x;
    const int bn   = blockIdx.x, bm = blockIdx.y;
    const int row0 = bm * BM, col0 = bn * BN;
    const int wid  = tid >> 6, lane = tid & 63;
    const int wr   = wid >> 1, wc = wid & 1;
    const int lr   = lane & 15, lg = lane >> 4;

    const int lrow = lane >> 2;           // 0..15 within 16-row chunk
    const int lcol = (lane & 3) * 8;      // 0,8,16,24

    f32x4 acc[4][4] = {};

    for (int k0 = 0; k0 < K; k0 += BK) {
        #pragma unroll
        for (int it = 0; it < 2; ++it) {
            const int c = wid * 2 + it;                     // 0..7
            const int r = c * 16 + lrow;
            gload16(&A [(size_t)(row0 + r) * K + k0 + lcol], &As[c * 512]);
            gload16(&Bt[(size_t)(col0 + r) * K + k0 + lcol], &Bs[c * 512]);
        }
        __syncthreads();

        bf16x8 bfr[4];
        #pragma unroll
        for (int n = 0; n < 4; ++n)
            bfr[n] = *(const bf16x8*)&Bs[(wc * 64 + n * 16 + lr) * BK + lg * 8];
        #pragma unroll
        for (int m = 0; m < 4; ++m) {
            bf16x8 a = *(const bf16x8*)&As[(wr * 64 + m * 16 + lr) * BK + lg * 8];
            #pragma unroll
            for (int n = 0; n < 4; ++n)
                acc[m][n] = __builtin_amdgcn_mfma_f32_16x16x32_bf16(a, bfr[n], acc[m][n], 0, 0, 0);
        }
        __syncthreads();
    }

    #pragma unroll
    for (int m = 0; m < 4; ++m) {
        int rowb = row0 + wr * 64 + m * 16 + lg * 4;
        #pragma unroll
        for (int n = 0; n < 4; ++n) {
            int col = col0 + wc * 64 + n * 16 + lr;
            #pragma unroll
            for (int i = 0; i < 4; ++i) {
                if (OUT_BF16)
                    ((ushort_t*)Cv)[(size_t)(rowb + i) * N + col] = f2bfu(acc[m][n][i]);
                else
                    ((float*)Cv)[(size_t)(rowb + i) * N + col] = acc[m][n][i];
            }
        }
    }
}

// ---------------------------------------------------------------------------
// Causal flash attention, swapped-QK^T 32x32x16 structure.
// One block = 128 q rows of one (b,h); 4 waves x 32 q rows. KV tiles of 64.
// bx REVERSED (heavy blocks dispatch first -> LPT load balance).
// T13 defer-max: skip O-rescale when wave-uniformly pm - m <= 64 (=8/scale).
// T5 setprio around MFMA clusters.
// ---------------------------------------------------------------------------
__global__ __launch_bounds__(256, 3) void attn_fwd(const ushort_t* __restrict__ qkv,
                                                   ushort_t* __restrict__ y) {
    const int bh = blockIdx.y;            // b*16 + h
    const int bx = (int)gridDim.x - 1 - (int)blockIdx.x;   // reversed: heavy first
    const int b  = bh >> 4, h = bh & 15;
    const int tid = threadIdx.x, wid = tid >> 6, lane = tid & 63;
    const int i  = lane & 31;             // q column within warp tile
    const int hh = lane >> 5;             // k-half selector
    const int bT = b * T_SEQ;

    __shared__ __align__(16) ushort_t Ks[64][72];   // [kv][dh]
    __shared__ __align__(16) ushort_t Vt[64][72];   // [dh][kv], kv-chunk XOR-swizzled by dh>>3

    const int q0 = bx * 128 + wid * 32;
    const int qg = q0 + i;

    // Q B-fragments: col=q (lane&31), k=dh = kd*16 + hh*8 + j
    bf16x8 qf[4];
    {
        const ushort_t* qrow = qkv + (size_t)(bT + qg) * EQKV + h * DH;
        #pragma unroll
        for (int kd = 0; kd < 4; ++kd)
            qf[kd] = *(const bf16x8*)&qrow[kd * 16 + hh * 8];
    }

    // staging coords: thread -> (kv row sr(+32), dh chunk sc)
    const int sr = tid >> 3;              // 0..31
    const int sc = (tid & 7) * 8;         // 0..56

    float m = -1e30f, lsum = 0.f;
    f32x16 o0 = {}, o1 = {};

    const int nt = 2 * bx + 2;            // kv tiles 0..nt-1

    // ---- stage tile 0 directly ----
    #pragma unroll
    for (int it = 0; it < 2; ++it) {
        int r = sr + 32 * it;
        const size_t go = (size_t)(bT + r) * EQKV + h * DH + sc;
        uint4 kk = *(const uint4*)&qkv[go + 1024];
        uint4 vv = *(const uint4*)&qkv[go + 2048];
        *(uint4*)&Ks[r][sc] = kk;
        const ushort_t* vs = (const ushort_t*)&vv;
        int chunk = r >> 3, br = r & 7;
        #pragma unroll
        for (int j = 0; j < 8; ++j) {
            int dh = sc + j;
            Vt[dh][((chunk ^ (dh >> 3)) << 3) | br] = vs[j];
        }
    }
    __syncthreads();

    for (int t = 0; t < nt; ++t) {
        const bool has_next = (t + 1 < nt);

        // prefetch next tile into registers (latency hidden under compute)
        uint4 kr[2], vr[2];
        if (has_next) {
            #pragma unroll
            for (int it = 0; it < 2; ++it) {
                const size_t go = (size_t)(bT + (t + 1) * 64 + sr + 32 * it) * EQKV + h * DH + sc;
                kr[it] = *(const uint4*)&qkv[go + 1024];
                vr[it] = *(const uint4*)&qkv[go + 2048];
            }
        }

        const int kmin = t * 64;
        const bool skip = kmin > q0 + 31;         // tile entirely above diagonal for this warp
        if (!skip) {
            const bool needmask = (kmin + 63) > q0;

            // ---- S^T = K * Q^T : two 32-kv groups, K-dim = dh (4 slices) ----
            f32x16 st[2] = {};
            __builtin_amdgcn_s_setprio(1);
            #pragma unroll
            for (int kd = 0; kd < 4; ++kd) {
                bf16x8 ka0 = *(const bf16x8*)&Ks[i][kd * 16 + hh * 8];
                bf16x8 ka1 = *(const bf16x8*)&Ks[32 + i][kd * 16 + hh * 8];
                st[0] = __builtin_amdgcn_mfma_f32_32x32x16_bf16(ka0, qf[kd], st[0], 0, 0, 0);
                st[1] = __builtin_amdgcn_mfma_f32_32x32x16_bf16(ka1, qf[kd], st[1], 0, 0, 0);
            }
            __builtin_amdgcn_s_setprio(0);

            // ---- mask + row max (row is lane-local + partner lane) ----
            float pm = -1e30f;
            #pragma unroll
            for (int g = 0; g < 2; ++g) {
                #pragma unroll
                for (int r = 0; r < 16; ++r) {
                    float v = st[g][r];
                    if (needmask) {
                        int kv = kmin + g * 32 + (r & 3) + 8 * (r >> 2) + 4 * hh;
                        v = (kv <= qg) ? v : -1e30f;
                        st[g][r] = v;
                    }
                    pm = fmaxf(pm, v);
                }
            }
            pm = fmaxf(pm, __shfl_xor(pm, 32));

            // ---- online softmax with defer-max (T13) ----
            // P = exp((S - m)*0.125); safe to keep old m while pm - m <= 64
            // (=> P <= e^8; f32 lsum/o have ample headroom).
            if (!__all(pm - m <= 64.f)) {
                const float mnew = fmaxf(m, pm);
                const float corr = __expf((m - mnew) * 0.125f);
                m = mnew;
                lsum *= corr;
                #pragma unroll
                for (int r = 0; r < 16; ++r) { o0[r] *= corr; o1[r] *= corr; }
            }
            float rs = 0.f;
            #pragma unroll
            for (int g = 0; g < 2; ++g) {
                #pragma unroll
                for (int r = 0; r < 16; ++r) {
                    float p = __expf((st[g][r] - m) * 0.125f);
                    st[g][r] = p;
                    rs += p;
                }
            }
            rs += __shfl_xor(rs, 32);
            lsum += rs;

            // ---- O^T += V^T * P^T over 4 kv-slices of 16 ----
            #pragma unroll
            for (int ks = 0; ks < 4; ++ks) {
                const int g = ks >> 1, b0 = (ks & 1) * 8;
                uint_t w0 = cvtpk(st[g][b0 + 0], st[g][b0 + 1]);
                uint_t w1 = cvtpk(st[g][b0 + 2], st[g][b0 + 3]);
                uint_t w2 = cvtpk(st[g][b0 + 4], st[g][b0 + 5]);
                uint_t w3 = cvtpk(st[g][b0 + 6], st[g][b0 + 7]);
                uint_t e0 = (uint_t)__shfl_xor((int)w0, 32);
                uint_t e1 = (uint_t)__shfl_xor((int)w1, 32);
                uint_t e2 = (uint_t)__shfl_xor((int)w2, 32);
                uint_t e3 = (uint_t)__shfl_xor((int)w3, 32);
                union { uint_t u[4]; bf16x8 v; } fr;
                fr.u[0] = hh ? e2 : w0;
                fr.u[1] = hh ? e3 : w1;
                fr.u[2] = hh ? w2 : e0;
                fr.u[3] = hh ? w3 : e1;
                const int cp0 = (((2 * ks + hh) ^ (i >> 3)) << 3);
                const int cp1 = (((2 * ks + hh) ^ (4 + (i >> 3))) << 3);
                bf16x8 va0 = *(const bf16x8*)&Vt[i][cp0];
                bf16x8 va1 = *(const bf16x8*)&Vt[32 + i][cp1];
                __builtin_amdgcn_s_setprio(1);
                o0 = __builtin_amdgcn_mfma_f32_32x32x16_bf16(va0, fr.v, o0, 0, 0, 0);
                o1 = __builtin_amdgcn_mfma_f32_32x32x16_bf16(va1, fr.v, o1, 0, 0, 0);
                __builtin_amdgcn_s_setprio(0);
            }
        }

        // ---- write prefetched tile to LDS ----
        if (has_next) {
            __syncthreads();              // all LDS reads of tile t done
            #pragma unroll
            for (int it = 0; it < 2; ++it) {
                int r = sr + 32 * it;
                *(uint4*)&Ks[r][sc] = kr[it];
                const ushort_t* vs = (const ushort_t*)&vr[it];
                int chunk = r >> 3, br = r & 7;
                #pragma unroll
                for (int j = 0; j < 8; ++j) {
                    int dh = sc + j;
                    Vt[dh][((chunk ^ (dh >> 3)) << 3) | br] = vs[j];
                }
            }
            __syncthreads();              // tile t+1 ready
        }
    }

    // ---- epilogue: normalize, pack bf16, store ----
    const float inv = 1.f / lsum;
    ushort_t* yrow = y + (size_t)(bT + qg) * (HEADS * DH) + h * DH;
    #pragma unroll
    for (int df = 0; df < 2; ++df) {
        const f32x16 oo = df ? o1 : o0;
        #pragma unroll
        for (int q4 = 0; q4 < 4; ++q4) {
            uint_t w0 = cvtpk(oo[q4 * 4 + 0] * inv, oo[q4 * 4 + 1] * inv);
            uint_t w1 = cvtpk(oo[q4 * 4 + 2] * inv, oo[q4 * 4 + 3] * inv);
            uint2 pk = make_uint2(w0, w1);
            *(uint2*)&yrow[df * 32 + q4 * 8 + hh * 4] = pk;
        }
    }
}

// ---------------------------------------------------------------------------
// launch
// ---------------------------------------------------------------------------
extern "C" void kernel_launch(void* const* d_in, const int* in_sizes, int n_in,
                              void* d_out, int out_size, void* d_ws, size_t ws_size,
                              hipStream_t stream) {
    const float* x     = (const float*)d_in[0];   // [B*T, 1024]
    const float* w_qkv = (const float*)d_in[1];   // [3072, 1024]
    const float* w_out = (const float*)d_in[2];   // [1024, 1024]

    const int BT = 4 * T_SEQ;                     // 8192

    char* ws = (char*)d_ws;
    ushort_t* xb   = (ushort_t*)(ws);
    ushort_t* wqb  = (ushort_t*)(ws + 16777216);
    ushort_t* wob  = (ushort_t*)(ws + 16777216 + 6291456);
    ushort_t* qkvb = (ushort_t*)(ws + 16777216 + 6291456 + 2097152);
    ushort_t* yb   = (ushort_t*)(ws + 16777216 + 6291456 + 2097152 + 50331648);

    // 1) convert inputs to bf16
    {
        int n4 = (BT * DMODEL) / 4;
        cvt_f32_bf16<<<(n4 + 255) / 256, 256, 0, stream>>>(x, xb, n4);
        n4 = (EQKV * DMODEL) / 4;
        cvt_f32_bf16<<<(n4 + 255) / 256, 256, 0, stream>>>(w_qkv, wqb, n4);
        n4 = (DMODEL * DMODEL) / 4;
        cvt_f32_bf16<<<(n4 + 255) / 256, 256, 0, stream>>>(w_out, wob, n4);
    }

    // 2) qkv = x @ w_qkv^T   (M=8192, N=3072, K=1024) -> bf16
    {
        dim3 grid(EQKV / BN, BT / BM);
        gemm_bt<true><<<grid, 256, 0, stream>>>(xb, wqb, (void*)qkvb, BT, EQKV, DMODEL);
    }

    // 3) flash attention -> y bf16 [BT][1024]
    {
        dim3 grid(T_SEQ / 128, 4 * HEADS);
        attn_fwd<<<grid, 256, 0, stream>>>(qkvb, yb);
    }

    // 4) out = y @ w_out^T   (M=8192, N=1024, K=1024) -> fp32
    {
        dim3 grid(DMODEL / BN, BT / BM);
        gemm_bt<false><<<grid, 256, 0, stream>>>(yb, wob, d_out, BT, DMODEL, DMODEL);
    }
}

// Round 6
// 333.873 us; speedup vs baseline: 1.1292x; 1.1292x over previous
//
#include <hip/hip_runtime.h>
#include <hip/hip_bf16.h>

// Problem constants (CausalSelfAttention): D_MODEL=1024, H=16, Dh=64, B=4, T=2048
#define T_SEQ   2048
#define HEADS   16
#define DH      64
#define DMODEL  1024
#define EQKV    3072   // 3*H*Dh

typedef __attribute__((ext_vector_type(8)))  __bf16 bf16x8;
typedef __attribute__((ext_vector_type(4)))  float  f32x4;
typedef __attribute__((ext_vector_type(16))) float  f32x16;
typedef unsigned short ushort_t;
typedef unsigned int   uint_t;

__device__ __forceinline__ ushort_t f2bfu(float x) {
    union { float f; uint_t u; } c; c.f = x;
    uint_t u = c.u;
    uint_t r = (u + 0x7fffu + ((u >> 16) & 1u)) >> 16;
    return (ushort_t)r;
}

// pack 2 f32 -> u32 holding 2 bf16 (lo = first arg)
__device__ __forceinline__ uint_t cvtpk(float lo, float hi) {
    uint_t r;
    asm volatile("v_cvt_pk_bf16_f32 %0, %1, %2" : "=v"(r) : "v"(lo), "v"(hi));
    return r;
}

// async global->LDS, 16B per lane; LDS dest is wave-uniform base + lane*16
__device__ __forceinline__ void gload16(const ushort_t* g, ushort_t* l) {
    __builtin_amdgcn_global_load_lds(
        (const __attribute__((address_space(1))) void*)g,
        (__attribute__((address_space(3))) void*)l,
        16, 0, 0);
}

// ---------------------------------------------------------------------------
// fp32 -> bf16 conversion (vectorized float4 in, 4 bf16 out)
// ---------------------------------------------------------------------------
__global__ void cvt_f32_bf16(const float* __restrict__ in, ushort_t* __restrict__ out, int n4) {
    int i = blockIdx.x * blockDim.x + threadIdx.x;
    if (i >= n4) return;
    const float4 v = ((const float4*)in)[i];
    ushort_t r0 = f2bfu(v.x), r1 = f2bfu(v.y), r2 = f2bfu(v.z), r3 = f2bfu(v.w);
    uint_t lo = (uint_t)r0 | ((uint_t)r1 << 16);
    uint_t hi = (uint_t)r2 | ((uint_t)r3 << 16);
    ((uint2*)out)[i] = make_uint2(lo, hi);
}

// ---------------------------------------------------------------------------
// bf16 GEMM: C[M][N] = A[M][K] * Bt[N][K]^T   (row-major bf16 raw ushort)
// 128x128 tile, BK=32, 4 waves (2x2), each wave 64x64 (4x4 16x16x32 frags).
// global_load_lds width-16 staging into linear [128][32] LDS (m97 structure).
// ---------------------------------------------------------------------------
#define BM 128
#define BN 128
#define BK 32

template<bool OUT_BF16>
__global__ __launch_bounds__(256) void gemm_bt(const ushort_t* __restrict__ A,
                                               const ushort_t* __restrict__ Bt,
                                               void* __restrict__ Cv,
                                               int M, int N, int K) {
    __shared__ __align__(16) ushort_t As[BM * BK];   // linear row-major 128x32
    __shared__ __align__(16) ushort_t Bs[BN * BK];

    const int tid  = threadIdx.x;
    const int bn   = blockIdx.x, bm = blockIdx.y;
    const int row0 = bm * BM, col0 = bn * BN;
    const int wid  = tid >> 6, lane = tid & 63;
    const int wr   = wid >> 1, wc = wid & 1;
    const int lr   = lane & 15, lg = lane >> 4;

    const int lrow = lane >> 2;           // 0..15 within 16-row chunk
    const int lcol = (lane & 3) * 8;      // 0,8,16,24

    f32x4 acc[4][4] = {};

    for (int k0 = 0; k0 < K; k0 += BK) {
        #pragma unroll
        for (int it = 0; it < 2; ++it) {
            const int c = wid * 2 + it;                     // 0..7
            const int r = c * 16 + lrow;
            gload16(&A [(size_t)(row0 + r) * K + k0 + lcol], &As[c * 512]);
            gload16(&Bt[(size_t)(col0 + r) * K + k0 + lcol], &Bs[c * 512]);
        }
        __syncthreads();

        bf16x8 bfr[4];
        #pragma unroll
        for (int n = 0; n < 4; ++n)
            bfr[n] = *(const bf16x8*)&Bs[(wc * 64 + n * 16 + lr) * BK + lg * 8];
        #pragma unroll
        for (int m = 0; m < 4; ++m) {
            bf16x8 a = *(const bf16x8*)&As[(wr * 64 + m * 16 + lr) * BK + lg * 8];
            #pragma unroll
            for (int n = 0; n < 4; ++n)
                acc[m][n] = __builtin_amdgcn_mfma_f32_16x16x32_bf16(a, bfr[n], acc[m][n], 0, 0, 0);
        }
        __syncthreads();
    }

    #pragma unroll
    for (int m = 0; m < 4; ++m) {
        int rowb = row0 + wr * 64 + m * 16 + lg * 4;
        #pragma unroll
        for (int n = 0; n < 4; ++n) {
            int col = col0 + wc * 64 + n * 16 + lr;
            #pragma unroll
            for (int i = 0; i < 4; ++i) {
                if (OUT_BF16)
                    ((ushort_t*)Cv)[(size_t)(rowb + i) * N + col] = f2bfu(acc[m][n][i]);
                else
                    ((float*)Cv)[(size_t)(rowb + i) * N + col] = acc[m][n][i];
            }
        }
    }
}

// ---------------------------------------------------------------------------
// Causal flash attention, swapped-QK^T 32x32x16 structure.
// One block = 64 q rows of one (b,h); 2 waves x 32 q rows. KV tiles of 64.
// 2048 blocks. Block remap (assumes round-robin dispatch, perf-only):
//   xcd = flat&7, s = flat>>3, bh = xcd*8 + (s&7), bx = 31 - (s>>3)
// => each CU hosts ONE (b,h) (KV 512KB reused from L2 by its 8 blocks) and
//    bx values {base, base+4, ..., base+28} (per-CU work balanced +-9%,
//    fixing the bx==const-per-CU imbalance that capped occupancy at 12%).
// Cross-half exchanges via __shfl_xor (round-4-proven). T13 defer-max; T5.
// ---------------------------------------------------------------------------
__global__ __launch_bounds__(128, 3) void attn_fwd(const ushort_t* __restrict__ qkv,
                                                   ushort_t* __restrict__ y) {
    const int flat = blockIdx.x;
    const int xcd  = flat & 7;
    const int s    = flat >> 3;              // 0..255
    const int bh   = xcd * 8 + (s & 7);      // 0..63  (b*16+h)
    const int bx   = 31 - (s >> 3);          // heavy-first within CU
    const int b    = bh >> 4, h = bh & 15;
    const int tid  = threadIdx.x, wid = tid >> 6, lane = tid & 63;
    const int i    = lane & 31;              // q column within warp tile
    const int hh   = lane >> 5;              // k-half selector
    const int bT   = b * T_SEQ;

    __shared__ __align__(16) ushort_t Ks[64][72];   // [kv][dh]
    __shared__ __align__(16) ushort_t Vt[64][72];   // [dh][kv], kv-chunk XOR-swizzled by dh>>3

    const int q0 = bx * 64 + wid * 32;
    const int qg = q0 + i;

    // Q B-fragments: col=q (lane&31), k=dh = kd*16 + hh*8 + j
    bf16x8 qf[4];
    {
        const ushort_t* qrow = qkv + (size_t)(bT + qg) * EQKV + h * DH;
        #pragma unroll
        for (int kd = 0; kd < 4; ++kd)
            qf[kd] = *(const bf16x8*)&qrow[kd * 16 + hh * 8];
    }

    float m = -1e30f, lsum = 0.f;
    f32x16 o0 = {}, o1 = {};

    const int nt = bx + 1;                   // kv tiles 0..bx

    // ---- stage tile 0 directly (128 threads: 4 chunks each per matrix) ----
    #pragma unroll
    for (int it = 0; it < 4; ++it) {
        const int idx = tid + it * 128;      // 0..511
        const int r   = idx >> 3;            // 0..63
        const int cc  = (idx & 7) * 8;       // 0..56
        const size_t go = (size_t)(bT + r) * EQKV + h * DH + cc;
        uint4 kk = *(const uint4*)&qkv[go + 1024];
        uint4 vv = *(const uint4*)&qkv[go + 2048];
        *(uint4*)&Ks[r][cc] = kk;
        const ushort_t* vs = (const ushort_t*)&vv;
        const int chunk = r >> 3, br = r & 7;
        #pragma unroll
        for (int j = 0; j < 8; ++j) {
            int dh = cc + j;
            Vt[dh][((chunk ^ (dh >> 3)) << 3) | br] = vs[j];
        }
    }
    __syncthreads();

    for (int t = 0; t < nt; ++t) {
        const bool has_next = (t + 1 < nt);

        // prefetch next tile into registers (latency hidden under compute)
        uint4 kr[4], vr[4];
        if (has_next) {
            #pragma unroll
            for (int it = 0; it < 4; ++it) {
                const int idx = tid + it * 128;
                const int r   = idx >> 3;
                const int cc  = (idx & 7) * 8;
                const size_t go = (size_t)(bT + (t + 1) * 64 + r) * EQKV + h * DH + cc;
                kr[it] = *(const uint4*)&qkv[go + 1024];
                vr[it] = *(const uint4*)&qkv[go + 2048];
            }
        }

        const int kmin = t * 64;
        {
            const bool needmask = (kmin + 63) > q0;

            // ---- S^T = K * Q^T : two 32-kv groups, K-dim = dh (4 slices) ----
            f32x16 st[2] = {};
            __builtin_amdgcn_s_setprio(1);
            #pragma unroll
            for (int kd = 0; kd < 4; ++kd) {
                bf16x8 ka0 = *(const bf16x8*)&Ks[i][kd * 16 + hh * 8];
                bf16x8 ka1 = *(const bf16x8*)&Ks[32 + i][kd * 16 + hh * 8];
                st[0] = __builtin_amdgcn_mfma_f32_32x32x16_bf16(ka0, qf[kd], st[0], 0, 0, 0);
                st[1] = __builtin_amdgcn_mfma_f32_32x32x16_bf16(ka1, qf[kd], st[1], 0, 0, 0);
            }
            __builtin_amdgcn_s_setprio(0);

            // ---- mask + row max (own half; partner half via shfl_xor 32) ----
            float pm = -1e30f;
            #pragma unroll
            for (int g = 0; g < 2; ++g) {
                #pragma unroll
                for (int r = 0; r < 16; ++r) {
                    float v = st[g][r];
                    if (needmask) {
                        int kv = kmin + g * 32 + (r & 3) + 8 * (r >> 2) + 4 * hh;
                        v = (kv <= qg) ? v : -1e30f;
                        st[g][r] = v;
                    }
                    pm = fmaxf(pm, v);
                }
            }
            pm = fmaxf(pm, __shfl_xor(pm, 32));

            // ---- online softmax with defer-max (T13): skip O-rescale while
            // pm - m <= 64 (scale 0.125 folded into exp => P <= e^8) ----
            if (!__all(pm - m <= 64.f)) {
                const float mnew = fmaxf(m, pm);
                const float corr = __expf((m - mnew) * 0.125f);
                m = mnew;
                lsum *= corr;
                #pragma unroll
                for (int r = 0; r < 16; ++r) { o0[r] *= corr; o1[r] *= corr; }
            }
            float rs = 0.f;
            #pragma unroll
            for (int g = 0; g < 2; ++g) {
                #pragma unroll
                for (int r = 0; r < 16; ++r) {
                    float p = __expf((st[g][r] - m) * 0.125f);
                    st[g][r] = p;
                    rs += p;
                }
            }
            rs += __shfl_xor(rs, 32);
            lsum += rs;

            // ---- O^T += V^T * P^T over 4 kv-slices of 16 ----
            #pragma unroll
            for (int ks = 0; ks < 4; ++ks) {
                const int g = ks >> 1, b0 = (ks & 1) * 8;
                uint_t w0 = cvtpk(st[g][b0 + 0], st[g][b0 + 1]);
                uint_t w1 = cvtpk(st[g][b0 + 2], st[g][b0 + 3]);
                uint_t w2 = cvtpk(st[g][b0 + 4], st[g][b0 + 5]);
                uint_t w3 = cvtpk(st[g][b0 + 6], st[g][b0 + 7]);
                uint_t e0 = (uint_t)__shfl_xor((int)w0, 32);
                uint_t e1 = (uint_t)__shfl_xor((int)w1, 32);
                uint_t e2 = (uint_t)__shfl_xor((int)w2, 32);
                uint_t e3 = (uint_t)__shfl_xor((int)w3, 32);
                union { uint_t u[4]; bf16x8 v; } fr;
                fr.u[0] = hh ? e2 : w0;
                fr.u[1] = hh ? e3 : w1;
                fr.u[2] = hh ? w2 : e0;
                fr.u[3] = hh ? w3 : e1;
                const int cp0 = (((2 * ks + hh) ^ (i >> 3)) << 3);
                const int cp1 = (((2 * ks + hh) ^ (4 + (i >> 3))) << 3);
                bf16x8 va0 = *(const bf16x8*)&Vt[i][cp0];
                bf16x8 va1 = *(const bf16x8*)&Vt[32 + i][cp1];
                __builtin_amdgcn_s_setprio(1);
                o0 = __builtin_amdgcn_mfma_f32_32x32x16_bf16(va0, fr.v, o0, 0, 0, 0);
                o1 = __builtin_amdgcn_mfma_f32_32x32x16_bf16(va1, fr.v, o1, 0, 0, 0);
                __builtin_amdgcn_s_setprio(0);
            }
        }

        // ---- write prefetched tile to LDS ----
        if (has_next) {
            __syncthreads();              // all LDS reads of tile t done
            #pragma unroll
            for (int it = 0; it < 4; ++it) {
                const int idx = tid + it * 128;
                const int r   = idx >> 3;
                const int cc  = (idx & 7) * 8;
                *(uint4*)&Ks[r][cc] = kr[it];
                const ushort_t* vs = (const ushort_t*)&vr[it];
                const int chunk = r >> 3, br = r & 7;
                #pragma unroll
                for (int j = 0; j < 8; ++j) {
                    int dh = cc + j;
                    Vt[dh][((chunk ^ (dh >> 3)) << 3) | br] = vs[j];
                }
            }
            __syncthreads();              // tile t+1 ready
        }
    }

    // ---- epilogue: normalize, pack bf16, store ----
    const float inv = 1.f / lsum;
    ushort_t* yrow = y + (size_t)(bT + qg) * (HEADS * DH) + h * DH;
    #pragma unroll
    for (int df = 0; df < 2; ++df) {
        const f32x16 oo = df ? o1 : o0;
        #pragma unroll
        for (int q4 = 0; q4 < 4; ++q4) {
            uint_t w0 = cvtpk(oo[q4 * 4 + 0] * inv, oo[q4 * 4 + 1] * inv);
            uint_t w1 = cvtpk(oo[q4 * 4 + 2] * inv, oo[q4 * 4 + 3] * inv);
            uint2 pk = make_uint2(w0, w1);
            *(uint2*)&yrow[df * 32 + q4 * 8 + hh * 4] = pk;
        }
    }
}

// ---------------------------------------------------------------------------
// launch
// ---------------------------------------------------------------------------
extern "C" void kernel_launch(void* const* d_in, const int* in_sizes, int n_in,
                              void* d_out, int out_size, void* d_ws, size_t ws_size,
                              hipStream_t stream) {
    const float* x     = (const float*)d_in[0];   // [B*T, 1024]
    const float* w_qkv = (const float*)d_in[1];   // [3072, 1024]
    const float* w_out = (const float*)d_in[2];   // [1024, 1024]

    const int BT = 4 * T_SEQ;                     // 8192

    char* ws = (char*)d_ws;
    ushort_t* xb   = (ushort_t*)(ws);
    ushort_t* wqb  = (ushort_t*)(ws + 16777216);
    ushort_t* wob  = (ushort_t*)(ws + 16777216 + 6291456);
    ushort_t* qkvb = (ushort_t*)(ws + 16777216 + 6291456 + 2097152);
    ushort_t* yb   = (ushort_t*)(ws + 16777216 + 6291456 + 2097152 + 50331648);

    // 1) convert inputs to bf16
    {
        int n4 = (BT * DMODEL) / 4;
        cvt_f32_bf16<<<(n4 + 255) / 256, 256, 0, stream>>>(x, xb, n4);
        n4 = (EQKV * DMODEL) / 4;
        cvt_f32_bf16<<<(n4 + 255) / 256, 256, 0, stream>>>(w_qkv, wqb, n4);
        n4 = (DMODEL * DMODEL) / 4;
        cvt_f32_bf16<<<(n4 + 255) / 256, 256, 0, stream>>>(w_out, wob, n4);
    }

    // 2) qkv = x @ w_qkv^T   (M=8192, N=3072, K=1024) -> bf16
    {
        dim3 grid(EQKV / BN, BT / BM);
        gemm_bt<true><<<grid, 256, 0, stream>>>(xb, wqb, (void*)qkvb, BT, EQKV, DMODEL);
    }

    // 3) flash attention -> y bf16 [BT][1024]
    {
        attn_fwd<<<2048, 128, 0, stream>>>(qkvb, yb);
    }

    // 4) out = y @ w_out^T   (M=8192, N=1024, K=1024) -> fp32
    {
        dim3 grid(DMODEL / BN, BT / BM);
        gemm_bt<false><<<grid, 256, 0, stream>>>(yb, wob, d_out, BT, DMODEL, DMODEL);
    }
}

// Round 7
// 306.761 us; speedup vs baseline: 1.2290x; 1.0884x over previous
//
#include <hip/hip_runtime.h>
#include <hip/hip_bf16.h>

// Problem constants (CausalSelfAttention): D_MODEL=1024, H=16, Dh=64, B=4, T=2048
#define T_SEQ   2048
#define HEADS   16
#define DH      64
#define DMODEL  1024
#define EQKV    3072   // 3*H*Dh

typedef __attribute__((ext_vector_type(8)))  __bf16 bf16x8;
typedef __attribute__((ext_vector_type(4)))  float  f32x4;
typedef __attribute__((ext_vector_type(16))) float  f32x16;
typedef unsigned short ushort_t;
typedef unsigned int   uint_t;

__device__ __forceinline__ ushort_t f2bfu(float x) {
    union { float f; uint_t u; } c; c.f = x;
    uint_t u = c.u;
    uint_t r = (u + 0x7fffu + ((u >> 16) & 1u)) >> 16;
    return (ushort_t)r;
}

// pack 2 f32 -> u32 holding 2 bf16 (lo = first arg)
__device__ __forceinline__ uint_t cvtpk(float lo, float hi) {
    uint_t r;
    asm volatile("v_cvt_pk_bf16_f32 %0, %1, %2" : "=v"(r) : "v"(lo), "v"(hi));
    return r;
}

// async global->LDS, 16B per lane; LDS dest is wave-uniform base + lane*16
__device__ __forceinline__ void gload16(const ushort_t* g, ushort_t* l) {
    __builtin_amdgcn_global_load_lds(
        (const __attribute__((address_space(1))) void*)g,
        (__attribute__((address_space(3))) void*)l,
        16, 0, 0);
}

// ---------------------------------------------------------------------------
// fp32 -> bf16 conversion (vectorized float4 in, 4 bf16 out)
// ---------------------------------------------------------------------------
__global__ void cvt_f32_bf16(const float* __restrict__ in, ushort_t* __restrict__ out, int n4) {
    int i = blockIdx.x * blockDim.x + threadIdx.x;
    if (i >= n4) return;
    const float4 v = ((const float4*)in)[i];
    ushort_t r0 = f2bfu(v.x), r1 = f2bfu(v.y), r2 = f2bfu(v.z), r3 = f2bfu(v.w);
    uint_t lo = (uint_t)r0 | ((uint_t)r1 << 16);
    uint_t hi = (uint_t)r2 | ((uint_t)r3 << 16);
    ((uint2*)out)[i] = make_uint2(lo, hi);
}

// ---------------------------------------------------------------------------
// bf16 GEMM: C[M][N] = A[M][K] * Bt[N][K]^T   (row-major bf16 raw ushort)
// 128x128 tile, BK=32, 4 waves (2x2), each wave 64x64 (4x4 16x16x32 frags).
// global_load_lds width-16 staging into linear [128][32] LDS (m97 structure).
// ---------------------------------------------------------------------------
#define BM 128
#define BN 128
#define BK 32

template<bool OUT_BF16>
__global__ __launch_bounds__(256) void gemm_bt(const ushort_t* __restrict__ A,
                                               const ushort_t* __restrict__ Bt,
                                               void* __restrict__ Cv,
                                               int M, int N, int K) {
    __shared__ __align__(16) ushort_t As[BM * BK];   // linear row-major 128x32
    __shared__ __align__(16) ushort_t Bs[BN * BK];

    const int tid  = threadIdx.x;
    const int bn   = blockIdx.x, bm = blockIdx.y;
    const int row0 = bm * BM, col0 = bn * BN;
    const int wid  = tid >> 6, lane = tid & 63;
    const int wr   = wid >> 1, wc = wid & 1;
    const int lr   = lane & 15, lg = lane >> 4;

    const int lrow = lane >> 2;           // 0..15 within 16-row chunk
    const int lcol = (lane & 3) * 8;      // 0,8,16,24

    f32x4 acc[4][4] = {};

    for (int k0 = 0; k0 < K; k0 += BK) {
        #pragma unroll
        for (int it = 0; it < 2; ++it) {
            const int c = wid * 2 + it;                     // 0..7
            const int r = c * 16 + lrow;
            gload16(&A [(size_t)(row0 + r) * K + k0 + lcol], &As[c * 512]);
            gload16(&Bt[(size_t)(col0 + r) * K + k0 + lcol], &Bs[c * 512]);
        }
        __syncthreads();

        bf16x8 bfr[4];
        #pragma unroll
        for (int n = 0; n < 4; ++n)
            bfr[n] = *(const bf16x8*)&Bs[(wc * 64 + n * 16 + lr) * BK + lg * 8];
        #pragma unroll
        for (int m = 0; m < 4; ++m) {
            bf16x8 a = *(const bf16x8*)&As[(wr * 64 + m * 16 + lr) * BK + lg * 8];
            #pragma unroll
            for (int n = 0; n < 4; ++n)
                acc[m][n] = __builtin_amdgcn_mfma_f32_16x16x32_bf16(a, bfr[n], acc[m][n], 0, 0, 0);
        }
        __syncthreads();
    }

    #pragma unroll
    for (int m = 0; m < 4; ++m) {
        int rowb = row0 + wr * 64 + m * 16 + lg * 4;
        #pragma unroll
        for (int n = 0; n < 4; ++n) {
            int col = col0 + wc * 64 + n * 16 + lr;
            #pragma unroll
            for (int i = 0; i < 4; ++i) {
                if (OUT_BF16)
                    ((ushort_t*)Cv)[(size_t)(rowb + i) * N + col] = f2bfu(acc[m][n][i]);
                else
                    ((float*)Cv)[(size_t)(rowb + i) * N + col] = acc[m][n][i];
            }
        }
    }
}

// ---------------------------------------------------------------------------
// Causal flash attention, swapped-QK^T 32x32x16 structure.
// One block = 64 q rows of one (b,h); 2 waves x 32 q rows. KV tiles of 64.
// Block remap (proven round 6): each CU hosts one (b,h), balanced bx set.
// NEW: double-buffered LDS; per tile: issue loads -> QK^T+softmax (covers
// HBM latency) -> write OTHER buffer (staging regs die before PV) -> PV ->
// ONE barrier. No long-lived prefetch registers => no scratch spill.
// launch_bounds(128,2): VGPR cap 256 (occupancy is LDS-bound at 4 blk/CU).
// ---------------------------------------------------------------------------
__global__ __launch_bounds__(128, 2) void attn_fwd(const ushort_t* __restrict__ qkv,
                                                   ushort_t* __restrict__ y) {
    const int flat = blockIdx.x;
    const int xcd  = flat & 7;
    const int s    = flat >> 3;              // 0..255
    const int bh   = xcd * 8 + (s & 7);      // 0..63  (b*16+h)
    const int bx   = 31 - (s >> 3);          // heavy-first within CU
    const int b    = bh >> 4, h = bh & 15;
    const int tid  = threadIdx.x, lane = tid & 63;
    const int wid  = tid >> 6;
    const int i    = lane & 31;              // q column within warp tile
    const int hh   = lane >> 5;              // k-half selector
    const int bT   = b * T_SEQ;

    __shared__ __align__(16) ushort_t Ks[2][64][72];   // [buf][kv][dh]
    __shared__ __align__(16) ushort_t Vt[2][64][72];   // [buf][dh][kv] XOR-swizzled

    const int q0 = bx * 64 + wid * 32;
    const int qg = q0 + i;

    // Q B-fragments: col=q (lane&31), k=dh = kd*16 + hh*8 + j
    bf16x8 qf[4];
    {
        const ushort_t* qrow = qkv + (size_t)(bT + qg) * EQKV + h * DH;
        #pragma unroll
        for (int kd = 0; kd < 4; ++kd)
            qf[kd] = *(const bf16x8*)&qrow[kd * 16 + hh * 8];
    }

    float m = -1e30f, lsum = 0.f;
    f32x16 o0 = {}, o1 = {};

    const int nt = bx + 1;                   // kv tiles 0..bx

    // ---- stage tile 0 into buffer 0 (128 threads: 4 chunks each) ----
    #pragma unroll
    for (int it = 0; it < 4; ++it) {
        const int idx = tid + it * 128;      // 0..511
        const int r   = idx >> 3;            // 0..63
        const int cc  = (idx & 7) * 8;       // 0..56
        const size_t go = (size_t)(bT + r) * EQKV + h * DH + cc;
        uint4 kk = *(const uint4*)&qkv[go + 1024];
        uint4 vv = *(const uint4*)&qkv[go + 2048];
        *(uint4*)&Ks[0][r][cc] = kk;
        const ushort_t* vs = (const ushort_t*)&vv;
        const int chunk = r >> 3, br = r & 7;
        #pragma unroll
        for (int j = 0; j < 8; ++j) {
            int dh = cc + j;
            Vt[0][dh][((chunk ^ (dh >> 3)) << 3) | br] = vs[j];
        }
    }
    __syncthreads();

    for (int t = 0; t < nt; ++t) {
        const int cb = t & 1, nb = cb ^ 1;
        const bool has_next = (t + 1 < nt);

        // ---- issue next tile's global loads (latency covered by QK^T+softmax)
        uint4 kr[4], vr[4];
        if (has_next) {
            #pragma unroll
            for (int it = 0; it < 4; ++it) {
                const int idx = tid + it * 128;
                const int r   = idx >> 3;
                const int cc  = (idx & 7) * 8;
                const size_t go = (size_t)(bT + (t + 1) * 64 + r) * EQKV + h * DH + cc;
                kr[it] = *(const uint4*)&qkv[go + 1024];
                vr[it] = *(const uint4*)&qkv[go + 2048];
            }
        }

        const int kmin = t * 64;
        const bool needmask = (kmin + 63) > q0;

        // ---- S^T = K * Q^T : two 32-kv groups, K-dim = dh (4 slices) ----
        f32x16 st[2] = {};
        __builtin_amdgcn_s_setprio(1);
        #pragma unroll
        for (int kd = 0; kd < 4; ++kd) {
            bf16x8 ka0 = *(const bf16x8*)&Ks[cb][i][kd * 16 + hh * 8];
            bf16x8 ka1 = *(const bf16x8*)&Ks[cb][32 + i][kd * 16 + hh * 8];
            st[0] = __builtin_amdgcn_mfma_f32_32x32x16_bf16(ka0, qf[kd], st[0], 0, 0, 0);
            st[1] = __builtin_amdgcn_mfma_f32_32x32x16_bf16(ka1, qf[kd], st[1], 0, 0, 0);
        }
        __builtin_amdgcn_s_setprio(0);

        // ---- mask + row max (own half; partner half via shfl_xor 32) ----
        float pm = -1e30f;
        #pragma unroll
        for (int g = 0; g < 2; ++g) {
            #pragma unroll
            for (int r = 0; r < 16; ++r) {
                float v = st[g][r];
                if (needmask) {
                    int kv = kmin + g * 32 + (r & 3) + 8 * (r >> 2) + 4 * hh;
                    v = (kv <= qg) ? v : -1e30f;
                    st[g][r] = v;
                }
                pm = fmaxf(pm, v);
            }
        }
        pm = fmaxf(pm, __shfl_xor(pm, 32));

        // ---- online softmax with defer-max (T13) ----
        if (!__all(pm - m <= 64.f)) {
            const float mnew = fmaxf(m, pm);
            const float corr = __expf((m - mnew) * 0.125f);
            m = mnew;
            lsum *= corr;
            #pragma unroll
            for (int r = 0; r < 16; ++r) { o0[r] *= corr; o1[r] *= corr; }
        }
        float rs = 0.f;
        #pragma unroll
        for (int g = 0; g < 2; ++g) {
            #pragma unroll
            for (int r = 0; r < 16; ++r) {
                float p = __expf((st[g][r] - m) * 0.125f);
                st[g][r] = p;
                rs += p;
            }
        }
        rs += __shfl_xor(rs, 32);
        lsum += rs;

        // ---- write next tile to the OTHER buffer; staging regs die here ----
        if (has_next) {
            #pragma unroll
            for (int it = 0; it < 4; ++it) {
                const int idx = tid + it * 128;
                const int r   = idx >> 3;
                const int cc  = (idx & 7) * 8;
                *(uint4*)&Ks[nb][r][cc] = kr[it];
                const ushort_t* vs = (const ushort_t*)&vr[it];
                const int chunk = r >> 3, br = r & 7;
                #pragma unroll
                for (int j = 0; j < 8; ++j) {
                    int dh = cc + j;
                    Vt[nb][dh][((chunk ^ (dh >> 3)) << 3) | br] = vs[j];
                }
            }
        }

        // ---- O^T += V^T * P^T over 4 kv-slices of 16 ----
        #pragma unroll
        for (int ks = 0; ks < 4; ++ks) {
            const int g = ks >> 1, b0 = (ks & 1) * 8;
            uint_t w0 = cvtpk(st[g][b0 + 0], st[g][b0 + 1]);
            uint_t w1 = cvtpk(st[g][b0 + 2], st[g][b0 + 3]);
            uint_t w2 = cvtpk(st[g][b0 + 4], st[g][b0 + 5]);
            uint_t w3 = cvtpk(st[g][b0 + 6], st[g][b0 + 7]);
            uint_t e0 = (uint_t)__shfl_xor((int)w0, 32);
            uint_t e1 = (uint_t)__shfl_xor((int)w1, 32);
            uint_t e2 = (uint_t)__shfl_xor((int)w2, 32);
            uint_t e3 = (uint_t)__shfl_xor((int)w3, 32);
            union { uint_t u[4]; bf16x8 v; } fr;
            fr.u[0] = hh ? e2 : w0;
            fr.u[1] = hh ? e3 : w1;
            fr.u[2] = hh ? w2 : e0;
            fr.u[3] = hh ? w3 : e1;
            const int cp0 = (((2 * ks + hh) ^ (i >> 3)) << 3);
            const int cp1 = (((2 * ks + hh) ^ (4 + (i >> 3))) << 3);
            bf16x8 va0 = *(const bf16x8*)&Vt[cb][i][cp0];
            bf16x8 va1 = *(const bf16x8*)&Vt[cb][32 + i][cp1];
            __builtin_amdgcn_s_setprio(1);
            o0 = __builtin_amdgcn_mfma_f32_32x32x16_bf16(va0, fr.v, o0, 0, 0, 0);
            o1 = __builtin_amdgcn_mfma_f32_32x32x16_bf16(va1, fr.v, o1, 0, 0, 0);
            __builtin_amdgcn_s_setprio(0);
        }

        // ---- single end-of-tile barrier: next buffer written & visible;
        //      this buffer's reads complete before tile t+2 overwrites it ----
        __syncthreads();
    }

    // ---- epilogue: normalize, pack bf16, store ----
    const float inv = 1.f / lsum;
    ushort_t* yrow = y + (size_t)(bT + qg) * (HEADS * DH) + h * DH;
    #pragma unroll
    for (int df = 0; df < 2; ++df) {
        const f32x16 oo = df ? o1 : o0;
        #pragma unroll
        for (int q4 = 0; q4 < 4; ++q4) {
            uint_t w0 = cvtpk(oo[q4 * 4 + 0] * inv, oo[q4 * 4 + 1] * inv);
            uint_t w1 = cvtpk(oo[q4 * 4 + 2] * inv, oo[q4 * 4 + 3] * inv);
            uint2 pk = make_uint2(w0, w1);
            *(uint2*)&yrow[df * 32 + q4 * 8 + hh * 4] = pk;
        }
    }
}

// ---------------------------------------------------------------------------
// launch
// ---------------------------------------------------------------------------
extern "C" void kernel_launch(void* const* d_in, const int* in_sizes, int n_in,
                              void* d_out, int out_size, void* d_ws, size_t ws_size,
                              hipStream_t stream) {
    const float* x     = (const float*)d_in[0];   // [B*T, 1024]
    const float* w_qkv = (const float*)d_in[1];   // [3072, 1024]
    const float* w_out = (const float*)d_in[2];   // [1024, 1024]

    const int BT = 4 * T_SEQ;                     // 8192

    char* ws = (char*)d_ws;
    ushort_t* xb   = (ushort_t*)(ws);
    ushort_t* wqb  = (ushort_t*)(ws + 16777216);
    ushort_t* wob  = (ushort_t*)(ws + 16777216 + 6291456);
    ushort_t* qkvb = (ushort_t*)(ws + 16777216 + 6291456 + 2097152);
    ushort_t* yb   = (ushort_t*)(ws + 16777216 + 6291456 + 2097152 + 50331648);

    // 1) convert inputs to bf16
    {
        int n4 = (BT * DMODEL) / 4;
        cvt_f32_bf16<<<(n4 + 255) / 256, 256, 0, stream>>>(x, xb, n4);
        n4 = (EQKV * DMODEL) / 4;
        cvt_f32_bf16<<<(n4 + 255) / 256, 256, 0, stream>>>(w_qkv, wqb, n4);
        n4 = (DMODEL * DMODEL) / 4;
        cvt_f32_bf16<<<(n4 + 255) / 256, 256, 0, stream>>>(w_out, wob, n4);
    }

    // 2) qkv = x @ w_qkv^T   (M=8192, N=3072, K=1024) -> bf16
    {
        dim3 grid(EQKV / BN, BT / BM);
        gemm_bt<true><<<grid, 256, 0, stream>>>(xb, wqb, (void*)qkvb, BT, EQKV, DMODEL);
    }

    // 3) flash attention -> y bf16 [BT][1024]
    {
        attn_fwd<<<2048, 128, 0, stream>>>(qkvb, yb);
    }

    // 4) out = y @ w_out^T   (M=8192, N=1024, K=1024) -> fp32
    {
        dim3 grid(DMODEL / BN, BT / BM);
        gemm_bt<false><<<grid, 256, 0, stream>>>(yb, wob, d_out, BT, DMODEL, DMODEL);
    }
}